// Round 7
// baseline (170.637 us; speedup 1.0000x reference)
//
#include <hip/hip_runtime.h>
#include <hip/hip_bf16.h>
#include <math.h>

#define BB 16
#define TT 256
#define CC 256
#define INNER 64
#define TPR 10
#define THD 32
#define EPSV 1e-5f

typedef __attribute__((ext_vector_type(8))) short short8;
typedef __attribute__((ext_vector_type(4))) float f32x4;
typedef __attribute__((ext_vector_type(4))) unsigned int u32x4;

__device__ __forceinline__ short f2bf(float f) {
    unsigned u = __float_as_uint(f);
    u += 0x7fffu + ((u >> 16) & 1);   // RNE
    return (short)(u >> 16);
}
__device__ __forceinline__ unsigned pkbf(float a, float b) {
    return (unsigned)(unsigned short)f2bf(a) | ((unsigned)(unsigned short)f2bf(b) << 16);
}

// ---------------- Kernel A: y = BN(x@W1+b1); skip=y; qkv = relu(y)@Wqkv ----------------
__global__ __launch_bounds__(256) void fc1_qkv_kernel(
    const float* __restrict__ x, const float* __restrict__ W1, const float* __restrict__ b1,
    const float* __restrict__ g1, const float* __restrict__ bb1,
    const float* __restrict__ m1, const float* __restrict__ v1,
    const float* __restrict__ Wqkv,
    float* __restrict__ skip, float* __restrict__ qkv)
{
    const int ROWS = 8;
    __shared__ float xr[ROWS][CC];
    __shared__ float yr[ROWS][CC];
    const int n0 = blockIdx.x * ROWS;
    const int t = threadIdx.x;

#pragma unroll
    for (int rr = 0; rr < ROWS; ++rr)
        xr[rr][t] = x[(size_t)(n0 + rr) * CC + t];
    __syncthreads();

    float acc[ROWS];
#pragma unroll
    for (int rr = 0; rr < ROWS; ++rr) acc[rr] = 0.f;
    for (int k = 0; k < CC; ++k) {
        float wv = W1[(size_t)k * CC + t];
#pragma unroll
        for (int rr = 0; rr < ROWS; ++rr) acc[rr] = fmaf(xr[rr][k], wv, acc[rr]);
    }
    const float s1 = g1[t] * rsqrtf(v1[t] + EPSV);
    const float base = b1[t] - m1[t];
    const float bet = bb1[t];
#pragma unroll
    for (int rr = 0; rr < ROWS; ++rr) {
        float y = (acc[rr] + base) * s1 + bet;
        skip[(size_t)(n0 + rr) * CC + t] = y;
        yr[rr][t] = fmaxf(y, 0.f);
    }
    __syncthreads();

    if (t < 192) {
        float a2[ROWS];
#pragma unroll
        for (int rr = 0; rr < ROWS; ++rr) a2[rr] = 0.f;
        for (int k = 0; k < CC; ++k) {
            float wv = Wqkv[(size_t)k * 192 + t];
#pragma unroll
            for (int rr = 0; rr < ROWS; ++rr) a2[rr] = fmaf(yr[rr][k], wv, a2[rr]);
        }
#pragma unroll
        for (int rr = 0; rr < ROWS; ++rr)
            qkv[(size_t)(n0 + rr) * 192 + t] = a2[rr];
    }
}

// ---------------- Kernel B: MFMA fused vector-attention (swapped operands) ----------------
// 1 block = 1 (b,i); 8 waves x 32 j-rows, fully wave-local between the staging barrier
// and the final reduction barrier. All GEMMs computed as D' = W^T @ data^T so each lane's
// D fragment is 4 consecutive channels of one j-row -> packed ds_write_b64 into row-major
// [j][ch] tiles (128B rows, mask-7 XOR swizzle; 2-way = free on reads and writes).
#define O_R    0        // r:   256 x 64B  (32 p-slots bf16, 10 real + zero pad), mask 3
#define O_TH   16384    // data 256 x 128B rows, mask 7: hid -> t -> h2 (reused, wave-local)
#define O_WT1  49152    // Wt1f^T 32 x 128B (K padded 10->32 in first 64B logical), mask 7
#define O_WT2  53248    // Wt2^T  64 x 128B (K=32, 64B logical), mask 7
#define O_WA1  61440    // Wa1^T  64 x 128B, mask 7
#define O_WA2  69632    // Wa2^T  64 x 128B, mask 7
#define O_RED  77824    // 8 waves x 4 tm x 4 q4 x 32B (num f32x4 + den f32x4)
#define LDSZ   81920    // 80KB -> exactly 2 blocks/CU

__device__ __forceinline__ int swb(int row, int cb, int sh, int mask) {
    return (row << sh) + (((cb & ~15) ^ ((row & mask) << 4)) | (cb & 15));
}
__device__ __forceinline__ short8 ldfrag(const char* lds, int base, int row, int cb16, int sh, int mask) {
    return *(const short8*)(lds + base + (row << sh) + (cb16 ^ ((row & mask) << 4)));
}

__global__ __launch_bounds__(512, 4) void attn_mfma_kernel(
    const float* __restrict__ r, const float* __restrict__ qkv,
    const float* __restrict__ Wt1, const float* __restrict__ bt1,
    const float* __restrict__ gt, const float* __restrict__ bbt,
    const float* __restrict__ mt, const float* __restrict__ vt,
    const float* __restrict__ Wt2, const float* __restrict__ bt2,
    const float* __restrict__ Wa1, const float* __restrict__ ba1,
    const float* __restrict__ Wa2, const float* __restrict__ ba2,
    float* __restrict__ agg)
{
    __shared__ __align__(16) char lds[LDSZ];
    const int n = blockIdx.x, b = n >> 8;
    const int tid = threadIdx.x;
    const int wv = tid >> 6, lane = tid & 63;
    const int lid = lane & 15, q4 = lane >> 4;
    const int kb = q4 * 16;          // byte offset of this quarter's 8-k slice in a 32-k row
    const int jt0 = wv * 2;          // wave's first j-tile (owns j in [wv*32, wv*32+32))

    // ---- phase 0: zero the K-padded regions (r rows, Wt1 rows)
    {
        u32x4 z = {0u, 0u, 0u, 0u};
        *(u32x4*)(lds + O_R + tid * 16) = z;
        *(u32x4*)(lds + O_R + 8192 + tid * 16) = z;
        if (tid < 256) *(u32x4*)(lds + O_WT1 + tid * 16) = z;
    }
    __syncthreads();

    // ---- phase 1: stage r (bf16) + transposed, BN-folded weights
    {
        const float* rrow = r + (size_t)n * (TT * TPR);
        for (int e = tid; e < TT * TPR; e += 512) {
            int j = e / TPR, p = e - j * TPR;
            *(short*)(lds + O_R + swb(j, p * 2, 6, 3)) = f2bf(rrow[e]);
        }
        if (tid < TPR * THD) {
            int p = tid >> 5, h = tid & 31;
            float scv = gt[h] * rsqrtf(vt[h] + EPSV);
            *(short*)(lds + O_WT1 + swb(h, p * 2, 7, 7)) = f2bf(Wt1[tid] * scv);
        }
        for (int e = tid; e < THD * INNER; e += 512) {
            int h = e >> 6, c = e & 63;
            *(short*)(lds + O_WT2 + swb(c, h * 2, 7, 7)) = f2bf(Wt2[e]);
        }
        for (int e = tid; e < INNER * INNER; e += 512) {
            int k = e >> 6, c = e & 63;
            *(short*)(lds + O_WA1 + swb(c, k * 2, 7, 7)) = f2bf(Wa1[e]);
            *(short*)(lds + O_WA2 + swb(c, k * 2, 7, 7)) = f2bf(Wa2[e]);
        }
    }
    __syncthreads();
    // ---------- everything below (until the reduction) is wave-local: no barriers ----------

    const float* kvb = qkv + (size_t)b * (TT * 192);
    const f32x4 z4 = {0.f, 0.f, 0.f, 0.f};

    // ---- GEMM1: hid[j][h] = relu((r @ Wt1f)[j][h] + c1[h]),   D' = Wt1f^T @ r^T
    {
        short8 aw0 = ldfrag(lds, O_WT1, lid, kb, 7, 7);
        short8 aw1 = ldfrag(lds, O_WT1, 16 + lid, kb, 7, 7);
        f32x4 acc1[2][2];
#pragma unroll
        for (int tn = 0; tn < 2; ++tn) {
            int j = (jt0 + tn) * 16 + lid;
            short8 bf = ldfrag(lds, O_R, j, kb, 6, 3);
            acc1[0][tn] = __builtin_amdgcn_mfma_f32_16x16x32_bf16(aw0, bf, z4, 0, 0, 0);
            acc1[1][tn] = __builtin_amdgcn_mfma_f32_16x16x32_bf16(aw1, bf, z4, 0, 0, 0);
        }
#pragma unroll
        for (int tm = 0; tm < 2; ++tm) {
            int ch0 = tm * 16 + q4 * 4;
            f32x4 g4 = *(const f32x4*)(gt + ch0);
            f32x4 vv4 = *(const f32x4*)(vt + ch0);
            f32x4 b4 = *(const f32x4*)(bt1 + ch0);
            f32x4 m4 = *(const f32x4*)(mt + ch0);
            f32x4 bb4 = *(const f32x4*)(bbt + ch0);
            f32x4 c1;
#pragma unroll
            for (int g = 0; g < 4; ++g)
                c1[g] = (b4[g] - m4[g]) * (g4[g] * rsqrtf(vv4[g] + EPSV)) + bb4[g];
#pragma unroll
            for (int tn = 0; tn < 2; ++tn) {
                int j = (jt0 + tn) * 16 + lid;
                float h0 = fmaxf(acc1[tm][tn][0] + c1[0], 0.f);
                float h1 = fmaxf(acc1[tm][tn][1] + c1[1], 0.f);
                float h2 = fmaxf(acc1[tm][tn][2] + c1[2], 0.f);
                float h3 = fmaxf(acc1[tm][tn][3] + c1[3], 0.f);
                uint2 w; w.x = pkbf(h0, h1); w.y = pkbf(h2, h3);
                *(uint2*)(lds + O_TH + swb(j, tm * 32 + q4 * 8, 7, 7)) = w;
            }
        }
    }

    // ---- GEMM2: rel[j][c] = (hid @ Wt2)[j][c] (+bt2 below), kept in VGPRs
    f32x4 rel[4][2];
    {
        short8 aw[4];
#pragma unroll
        for (int tm = 0; tm < 4; ++tm)
            aw[tm] = ldfrag(lds, O_WT2, tm * 16 + lid, kb, 7, 7);
#pragma unroll
        for (int tn = 0; tn < 2; ++tn) {
            int j = (jt0 + tn) * 16 + lid;
            short8 bf = ldfrag(lds, O_TH, j, kb, 7, 7);
#pragma unroll
            for (int tm = 0; tm < 4; ++tm)
                rel[tm][tn] = __builtin_amdgcn_mfma_f32_16x16x32_bf16(aw[tm], bf, z4, 0, 0, 0);
        }
    }
    // t[j][c] = q[c] - k[j][c] + rel  -> packed bf16 into O_TH (overwrites hid: wave-local)
#pragma unroll
    for (int tm = 0; tm < 4; ++tm) {
        int ch0 = tm * 16 + q4 * 4;
        f32x4 bt24 = *(const f32x4*)(bt2 + ch0);
        f32x4 qv4 = *(const f32x4*)(qkv + (size_t)n * 192 + ch0);
#pragma unroll
        for (int tn = 0; tn < 2; ++tn) {
            int j = (jt0 + tn) * 16 + lid;
            f32x4 kv4 = *(const f32x4*)(kvb + (size_t)j * 192 + 64 + ch0);
            float t0, t1, t2, t3;
#pragma unroll
            for (int g = 0; g < 4; ++g) rel[tm][tn][g] += bt24[g];
            t0 = qv4[0] - kv4[0] + rel[tm][tn][0];
            t1 = qv4[1] - kv4[1] + rel[tm][tn][1];
            t2 = qv4[2] - kv4[2] + rel[tm][tn][2];
            t3 = qv4[3] - kv4[3] + rel[tm][tn][3];
            uint2 w; w.x = pkbf(t0, t1); w.y = pkbf(t2, t3);
            *(uint2*)(lds + O_TH + swb(j, tm * 32 + q4 * 8, 7, 7)) = w;
        }
    }

    // ---- GEMM3: h2 = relu(t @ Wa1 + ba1)  (all 8 tiles accumulated before overwrite)
    f32x4 acc[4][2];
#pragma unroll
    for (int tm = 0; tm < 4; ++tm)
#pragma unroll
        for (int tn = 0; tn < 2; ++tn) acc[tm][tn] = z4;
#pragma unroll
    for (int ks = 0; ks < 2; ++ks) {
        short8 aw[4];
#pragma unroll
        for (int tm = 0; tm < 4; ++tm)
            aw[tm] = ldfrag(lds, O_WA1, tm * 16 + lid, ks * 64 + kb, 7, 7);
#pragma unroll
        for (int tn = 0; tn < 2; ++tn) {
            int j = (jt0 + tn) * 16 + lid;
            short8 bf = ldfrag(lds, O_TH, j, ks * 64 + kb, 7, 7);
#pragma unroll
            for (int tm = 0; tm < 4; ++tm)
                acc[tm][tn] = __builtin_amdgcn_mfma_f32_16x16x32_bf16(aw[tm], bf, acc[tm][tn], 0, 0, 0);
        }
    }
#pragma unroll
    for (int tm = 0; tm < 4; ++tm) {
        int ch0 = tm * 16 + q4 * 4;
        f32x4 ba14 = *(const f32x4*)(ba1 + ch0);
#pragma unroll
        for (int tn = 0; tn < 2; ++tn) {
            int j = (jt0 + tn) * 16 + lid;
            float h0 = fmaxf(acc[tm][tn][0] + ba14[0], 0.f);
            float h1 = fmaxf(acc[tm][tn][1] + ba14[1], 0.f);
            float h2 = fmaxf(acc[tm][tn][2] + ba14[2], 0.f);
            float h3 = fmaxf(acc[tm][tn][3] + ba14[3], 0.f);
            uint2 w; w.x = pkbf(h0, h1); w.y = pkbf(h2, h3);
            *(uint2*)(lds + O_TH + swb(j, tm * 32 + q4 * 8, 7, 7)) = w;
        }
    }

    // ---- GEMM4: sim = h2 @ Wa2  (ba2 cancels in softmax over j)
#pragma unroll
    for (int tm = 0; tm < 4; ++tm)
#pragma unroll
        for (int tn = 0; tn < 2; ++tn) acc[tm][tn] = z4;
#pragma unroll
    for (int ks = 0; ks < 2; ++ks) {
        short8 aw[4];
#pragma unroll
        for (int tm = 0; tm < 4; ++tm)
            aw[tm] = ldfrag(lds, O_WA2, tm * 16 + lid, ks * 64 + kb, 7, 7);
#pragma unroll
        for (int tn = 0; tn < 2; ++tn) {
            int j = (jt0 + tn) * 16 + lid;
            short8 bf = ldfrag(lds, O_TH, j, ks * 64 + kb, 7, 7);
#pragma unroll
            for (int tm = 0; tm < 4; ++tm)
                acc[tm][tn] = __builtin_amdgcn_mfma_f32_16x16x32_bf16(aw[tm], bf, acc[tm][tn], 0, 0, 0);
        }
    }

    // ---- softmax over j (no max-sub; sim is small) + weighted vv sum; per-tm to cap regs
#pragma unroll
    for (int tm = 0; tm < 4; ++tm) {
        const int ch0 = tm * 16 + q4 * 4;
        f32x4 num = z4, den = z4;
#pragma unroll
        for (int tn = 0; tn < 2; ++tn) {
            int j = (jt0 + tn) * 16 + lid;
            f32x4 v4 = *(const f32x4*)(kvb + (size_t)j * 192 + 128 + ch0);
#pragma unroll
            for (int g = 0; g < 4; ++g) {
                float ev = __expf(acc[tm][tn][g]);
                den[g] += ev;
                num[g] = fmaf(ev, v4[g] + rel[tm][tn][g], num[g]);
            }
        }
#pragma unroll
        for (int ofs = 1; ofs < 16; ofs <<= 1) {
#pragma unroll
            for (int g = 0; g < 4; ++g) {
                num[g] += __shfl_xor(num[g], ofs);
                den[g] += __shfl_xor(den[g], ofs);
            }
        }
        if (lid == 0) {
            int base = O_RED + ((wv * 4 + tm) * 4 + q4) * 32;
            *(f32x4*)(lds + base) = num;
            *(f32x4*)(lds + base + 16) = den;
        }
    }
    __syncthreads();

    if (tid < 64) {
        int tm = tid >> 4, qq = (tid >> 2) & 3, g = tid & 3;
        float nn = 0.f, dd = 0.f;
#pragma unroll
        for (int w = 0; w < 8; ++w) {
            int base = O_RED + ((w * 4 + tm) * 4 + qq) * 32 + g * 4;
            nn += *(const float*)(lds + base);
            dd += *(const float*)(lds + base + 16);
        }
        agg[(size_t)n * 64 + tid] = nn / dd;
    }
}

// ---------------- Kernel C: out = relu(BN(agg@W2+b2) + skip) ----------------
__global__ __launch_bounds__(256) void fc2_kernel(
    const float* __restrict__ agg, const float* __restrict__ W2, const float* __restrict__ b2,
    const float* __restrict__ g2, const float* __restrict__ bb2,
    const float* __restrict__ m2, const float* __restrict__ v2,
    const float* __restrict__ skip, float* __restrict__ out)
{
    const int ROWS = 8;
    __shared__ float ar[ROWS][INNER];
    const int n0 = blockIdx.x * ROWS;
    const int t = threadIdx.x;

    for (int idx = t; idx < ROWS * INNER; idx += 256)
        ((float*)ar)[idx] = agg[(size_t)n0 * INNER + idx];
    __syncthreads();

    const float s2 = g2[t] * rsqrtf(v2[t] + EPSV);
    const float base = b2[t] - m2[t];
    const float bet = bb2[t];

    float accv[ROWS];
#pragma unroll
    for (int rr = 0; rr < ROWS; ++rr) accv[rr] = 0.f;
    for (int k = 0; k < INNER; ++k) {
        float wv = W2[(size_t)k * CC + t];
#pragma unroll
        for (int rr = 0; rr < ROWS; ++rr) accv[rr] = fmaf(ar[rr][k], wv, accv[rr]);
    }
#pragma unroll
    for (int rr = 0; rr < ROWS; ++rr) {
        float y = (accv[rr] + base) * s2 + bet;
        out[(size_t)(n0 + rr) * CC + t] =
            fmaxf(y + skip[(size_t)(n0 + rr) * CC + t], 0.f);
    }
}

extern "C" void kernel_launch(void* const* d_in, const int* in_sizes, int n_in,
                              void* d_out, int out_size, void* d_ws, size_t ws_size,
                              hipStream_t stream)
{
    const float* x   = (const float*)d_in[0];
    const float* r   = (const float*)d_in[1];
    const float* W1  = (const float*)d_in[2];
    const float* b1  = (const float*)d_in[3];
    const float* g1  = (const float*)d_in[4];
    const float* bb1 = (const float*)d_in[5];
    const float* m1  = (const float*)d_in[6];
    const float* v1  = (const float*)d_in[7];
    const float* Wqkv= (const float*)d_in[8];
    const float* Wt1 = (const float*)d_in[9];
    const float* bt1 = (const float*)d_in[10];
    const float* gt  = (const float*)d_in[11];
    const float* bbt = (const float*)d_in[12];
    const float* mt  = (const float*)d_in[13];
    const float* vt  = (const float*)d_in[14];
    const float* Wt2 = (const float*)d_in[15];
    const float* bt2 = (const float*)d_in[16];
    const float* Wa1 = (const float*)d_in[17];
    const float* ba1 = (const float*)d_in[18];
    const float* Wa2 = (const float*)d_in[19];
    const float* ba2 = (const float*)d_in[20];
    const float* W2  = (const float*)d_in[21];
    const float* b2  = (const float*)d_in[22];
    const float* g2  = (const float*)d_in[23];
    const float* bb2 = (const float*)d_in[24];
    const float* m2  = (const float*)d_in[25];
    const float* v2  = (const float*)d_in[26];
    float* out = (float*)d_out;

    const int N = BB * TT;                 // 4096 rows
    float* skip = (float*)d_ws;            // N*256 floats = 4 MB
    float* qkv  = skip + (size_t)N * CC;   // N*192 floats = 3 MB
    float* agg  = qkv  + (size_t)N * 192;  // N*64  floats = 1 MB

    fc1_qkv_kernel<<<dim3(N / 8), dim3(256), 0, stream>>>(
        x, W1, b1, g1, bb1, m1, v1, Wqkv, skip, qkv);
    attn_mfma_kernel<<<dim3(N), dim3(512), 0, stream>>>(
        r, qkv, Wt1, bt1, gt, bbt, mt, vt, Wt2, bt2, Wa1, ba1, Wa2, ba2, agg);
    fc2_kernel<<<dim3(N / 8), dim3(256), 0, stream>>>(
        agg, W2, b2, g2, bb2, m2, v2, skip, out);
}

// Round 8
// 160.493 us; speedup vs baseline: 1.0632x; 1.0632x over previous
//
#include <hip/hip_runtime.h>
#include <hip/hip_bf16.h>
#include <math.h>

#define BB 16
#define TT 256
#define CC 256
#define INNER 64
#define TPR 10
#define THD 32
#define EPSV 1e-5f

typedef __attribute__((ext_vector_type(8))) short short8;
typedef __attribute__((ext_vector_type(4))) float f32x4;

__device__ __forceinline__ short f2bf(float f) {
    unsigned u = __float_as_uint(f);
    u += 0x7fffu + ((u >> 16) & 1);   // RNE
    return (short)(u >> 16);
}
__device__ __forceinline__ unsigned cvtpk(float a, float b) {
    __hip_bfloat162 h = __float22bfloat162_rn(float2{a, b});
    return *(unsigned*)&h;
}

// ---- weight image byte offsets (in ws) ----
#define IMG_WT1  0        // [32 m][32 k] bf16 linear (k>=10 zero)
#define IMG_WT2  2048     // [c>>1][128B] paired rows, mask-7 swizzle
#define IMG_WA1  6144     // [64 c][128B] mask-7 swizzle
#define IMG_WA2  14336
#define IMG_C1   22528    // f32[32]
#define IMG_SZ   22656

__device__ __forceinline__ int sww(int pb, int key) {
    return ((pb & ~15) ^ key) | (pb & 15);
}

// ---------------- prep: build bf16 pre-swizzled weight images + folded BN ----------------
__global__ __launch_bounds__(256) void prep_kernel(
    const float* __restrict__ Wt1, const float* __restrict__ bt1,
    const float* __restrict__ gt, const float* __restrict__ bbt,
    const float* __restrict__ mt, const float* __restrict__ vt,
    const float* __restrict__ Wt2, const float* __restrict__ Wa1,
    const float* __restrict__ Wa2, char* __restrict__ img)
{
    const int blk = blockIdx.x, t = threadIdx.x;
    if (blk == 0) {
        for (int e = t; e < 32 * 32; e += 256) {
            int m = e >> 5, k = e & 31;
            float scv = gt[m] * rsqrtf(vt[m] + EPSV);
            float v = (k < TPR) ? Wt1[k * 32 + m] * scv : 0.f;
            *(short*)(img + IMG_WT1 + m * 64 + k * 2) = f2bf(v);
        }
        if (t < 32) {
            float scv = gt[t] * rsqrtf(vt[t] + EPSV);
            ((float*)(img + IMG_C1))[t] = (bt1[t] - mt[t]) * scv + bbt[t];
        }
    } else if (blk == 1) {
        for (int e = t; e < 32 * 64; e += 256) {
            int h = e >> 6, c = e & 63;
            int off = IMG_WT2 + (c >> 1) * 128 + sww((c & 1) * 64 + h * 2, ((c >> 1) & 7) << 4);
            *(short*)(img + off) = f2bf(Wt2[e]);
        }
    } else {
        const float* W = (blk == 2) ? Wa1 : Wa2;
        int base = (blk == 2) ? IMG_WA1 : IMG_WA2;
        for (int e = t; e < 64 * 64; e += 256) {
            int k = e >> 6, c = e & 63;
            int off = base + c * 128 + sww(k * 2, (c & 7) << 4);
            *(short*)(img + off) = f2bf(W[e]);
        }
    }
}

// ---------------- Kernel A: y = BN(x@W1+b1); skip=y; qkv = relu(y)@Wqkv ----------------
__global__ __launch_bounds__(256) void fc1_qkv_kernel(
    const float* __restrict__ x, const float* __restrict__ W1, const float* __restrict__ b1,
    const float* __restrict__ g1, const float* __restrict__ bb1,
    const float* __restrict__ m1, const float* __restrict__ v1,
    const float* __restrict__ Wqkv,
    float* __restrict__ skip, float* __restrict__ qkv)
{
    const int ROWS = 8;
    __shared__ float xr[ROWS][CC];
    __shared__ float yr[ROWS][CC];
    const int n0 = blockIdx.x * ROWS;
    const int t = threadIdx.x;

#pragma unroll
    for (int rr = 0; rr < ROWS; ++rr)
        xr[rr][t] = x[(size_t)(n0 + rr) * CC + t];
    __syncthreads();

    float acc[ROWS];
#pragma unroll
    for (int rr = 0; rr < ROWS; ++rr) acc[rr] = 0.f;
    for (int k = 0; k < CC; ++k) {
        float wv = W1[(size_t)k * CC + t];
#pragma unroll
        for (int rr = 0; rr < ROWS; ++rr) acc[rr] = fmaf(xr[rr][k], wv, acc[rr]);
    }
    const float s1 = g1[t] * rsqrtf(v1[t] + EPSV);
    const float base = b1[t] - m1[t];
    const float bet = bb1[t];
#pragma unroll
    for (int rr = 0; rr < ROWS; ++rr) {
        float y = (acc[rr] + base) * s1 + bet;
        skip[(size_t)(n0 + rr) * CC + t] = y;
        yr[rr][t] = fmaxf(y, 0.f);
    }
    __syncthreads();

    if (t < 192) {
        float a2[ROWS];
#pragma unroll
        for (int rr = 0; rr < ROWS; ++rr) a2[rr] = 0.f;
        for (int k = 0; k < CC; ++k) {
            float wv = Wqkv[(size_t)k * 192 + t];
#pragma unroll
            for (int rr = 0; rr < ROWS; ++rr) a2[rr] = fmaf(yr[rr][k], wv, a2[rr]);
        }
#pragma unroll
        for (int rr = 0; rr < ROWS; ++rr)
            qkv[(size_t)(n0 + rr) * 192 + t] = a2[rr];
    }
}

// ---------------- Kernel B: MFMA fused vector-attention ----------------
#define O_R    0        // r: [256 j][64B] bf16 K=32 padded, linear
#define O_TH   16384    // [256 j][128B] mask-7: hid -> t -> h2 (wave-local reuse)
#define O_WT1  49152    // 2KB  [32 m][32 k] linear
#define O_WT2  51200    // 4KB  paired rows mask-7
#define O_WA1  55296    // 8KB  [64 c][64 k] mask-7
#define O_WA2  63488    // 8KB
#define O_RED  71680    // 4KB
#define LDSZ   75776

__device__ __forceinline__ int swb(int row, int cb, int sh, int mask) {
    return (row << sh) + (((cb & ~15) ^ ((row & mask) << 4)) | (cb & 15));
}
__device__ __forceinline__ short8 ldfrag(const char* lds, int base, int row, int cb16, int sh, int mask) {
    return *(const short8*)(lds + base + (row << sh) + (cb16 ^ ((row & mask) << 4)));
}

__global__ __launch_bounds__(512, 4) void attn_mfma_kernel(
    const float* __restrict__ r, const float* __restrict__ qkv,
    const float* __restrict__ bt2, const float* __restrict__ ba1,
    const char* __restrict__ img, float* __restrict__ agg)
{
    __shared__ __align__(16) char lds[LDSZ];
    const int n = blockIdx.x, b = n >> 8;
    const int tid = threadIdx.x;
    const int wv = tid >> 6, lane = tid & 63;
    const int lid = lane & 15, q4 = lane >> 4;
    const int kb = q4 * 16;
    const int jt0 = wv * 2;

    const float* kvb = qkv + (size_t)b * (TT * 192);
    const f32x4 z4 = {0.f, 0.f, 0.f, 0.f};

    // ---- async weight staging: 22 x 1KB chunks via global_load_lds (pre-swizzled image)
#pragma unroll
    for (int ci = 0; ci < 3; ++ci) {
        int c = wv + ci * 8;
        if (c < 22) {
            int ldsoff;
            if (c < 2)       ldsoff = O_WT1 + c * 1024;
            else if (c < 6)  ldsoff = O_WT2 + (c - 2) * 1024;
            else if (c < 14) ldsoff = O_WA1 + (c - 6) * 1024;
            else             ldsoff = O_WA2 + (c - 14) * 1024;
            __builtin_amdgcn_global_load_lds(
                (const __attribute__((address_space(1))) unsigned*)(const unsigned*)(img + c * 1024 + lane * 16),
                (__attribute__((address_space(3))) unsigned*)(unsigned*)(lds + ldsoff + lane * 16),
                16, 0, 0);
        }
    }

    // ---- hoisted k loads (consumed in GEMM2 epilogue)
    f32x4 k4[4][2];
#pragma unroll
    for (int tm = 0; tm < 4; ++tm) {
        int ch0 = tm * 16 + q4 * 4;
#pragma unroll
        for (int tn = 0; tn < 2; ++tn) {
            int j = (jt0 + tn) * 16 + lid;
            k4[tm][tn] = *(const f32x4*)(kvb + (size_t)j * 192 + 64 + ch0);
        }
    }

    // ---- r staging: thread = (row, half); 5 consecutive floats, no division
    {
        const float* rrow = r + (size_t)n * (TT * TPR);
        int j = tid >> 1, half = tid & 1;
        const float* rp = rrow + j * TPR + half * 5;
        float v0 = rp[0], v1 = rp[1], v2 = rp[2], v3 = rp[3], v4 = rp[4];
        char* rb = lds + O_R + j * 64;
        if (half == 0) {
            uint2 w; w.x = cvtpk(v0, v1); w.y = cvtpk(v2, v3);
            *(uint2*)(rb) = w;
            *(unsigned short*)(rb + 8) = (unsigned short)f2bf(v4);
        } else {
            *(unsigned short*)(rb + 10) = (unsigned short)f2bf(v0);
            *(unsigned*)(rb + 12) = cvtpk(v1, v2);
            *(unsigned*)(rb + 16) = cvtpk(v3, v4);
            *(unsigned*)(rb + 20) = 0u;
            uint2 zz; zz.x = 0u; zz.y = 0u;
            *(uint2*)(rb + 24) = zz;
            *(uint2*)(rb + 32) = zz;
            *(uint2*)(rb + 40) = zz;
            *(uint2*)(rb + 48) = zz;
            *(uint2*)(rb + 56) = zz;
        }
    }
    __syncthreads();
    // ---------- wave-local from here until final reduction ----------

    const float* c1g = (const float*)(img + IMG_C1);

    // ---- GEMM1: hid = relu(Wt1f^T @ r^T)  (c1 in C-operand)
    {
        short8 a10 = ldfrag(lds, O_WT1, lid, kb, 6, 0);
        short8 a11 = ldfrag(lds, O_WT1, 16 + lid, kb, 6, 0);
        f32x4 c1v0 = *(const f32x4*)(c1g + q4 * 4);
        f32x4 c1v1 = *(const f32x4*)(c1g + 16 + q4 * 4);
        f32x4 acc1[2][2];
#pragma unroll
        for (int tn = 0; tn < 2; ++tn) {
            int j = (jt0 + tn) * 16 + lid;
            short8 bf = ldfrag(lds, O_R, j, kb, 6, 0);
            acc1[0][tn] = __builtin_amdgcn_mfma_f32_16x16x32_bf16(a10, bf, c1v0, 0, 0, 0);
            acc1[1][tn] = __builtin_amdgcn_mfma_f32_16x16x32_bf16(a11, bf, c1v1, 0, 0, 0);
        }
#pragma unroll
        for (int tm = 0; tm < 2; ++tm)
#pragma unroll
            for (int tn = 0; tn < 2; ++tn) {
                int j = (jt0 + tn) * 16 + lid;
                uint2 w;
                w.x = cvtpk(fmaxf(acc1[tm][tn][0], 0.f), fmaxf(acc1[tm][tn][1], 0.f));
                w.y = cvtpk(fmaxf(acc1[tm][tn][2], 0.f), fmaxf(acc1[tm][tn][3], 0.f));
                *(uint2*)(lds + O_TH + swb(j, tm * 32 + q4 * 8, 7, 7)) = w;
            }
    }

    // ---- load q + bt2 (used in GEMM2 epilogue / C-init)
    f32x4 qv4[4], bt2v[4];
#pragma unroll
    for (int tm = 0; tm < 4; ++tm) {
        int ch0 = tm * 16 + q4 * 4;
        qv4[tm] = *(const f32x4*)(qkv + (size_t)n * 192 + ch0);
        bt2v[tm] = *(const f32x4*)(bt2 + ch0);
    }

    // ---- GEMM2: rel = Wt2^T @ hid^T + bt2 (in C); kept in VGPRs
    f32x4 rel[4][2];
    {
        short8 aw[4];
#pragma unroll
        for (int tm = 0; tm < 4; ++tm) {
            int c = tm * 16 + lid;
            aw[tm] = ldfrag(lds, O_WT2, c >> 1, (c & 1) * 64 + kb, 7, 7);
        }
#pragma unroll
        for (int tn = 0; tn < 2; ++tn) {
            int j = (jt0 + tn) * 16 + lid;
            short8 bf = ldfrag(lds, O_TH, j, kb, 7, 7);
#pragma unroll
            for (int tm = 0; tm < 4; ++tm)
                rel[tm][tn] = __builtin_amdgcn_mfma_f32_16x16x32_bf16(aw[tm], bf, bt2v[tm], 0, 0, 0);
        }
    }
    // t = q - k + rel -> packed bf16 (overwrites hid rows; wave-local, DS in-order)
#pragma unroll
    for (int tm = 0; tm < 4; ++tm)
#pragma unroll
        for (int tn = 0; tn < 2; ++tn) {
            int j = (jt0 + tn) * 16 + lid;
            float t0 = qv4[tm][0] - k4[tm][tn][0] + rel[tm][tn][0];
            float t1 = qv4[tm][1] - k4[tm][tn][1] + rel[tm][tn][1];
            float t2 = qv4[tm][2] - k4[tm][tn][2] + rel[tm][tn][2];
            float t3 = qv4[tm][3] - k4[tm][tn][3] + rel[tm][tn][3];
            uint2 w; w.x = cvtpk(t0, t1); w.y = cvtpk(t2, t3);
            *(uint2*)(lds + O_TH + swb(j, tm * 32 + q4 * 8, 7, 7)) = w;
        }

    // ---- GEMM3: h2 = relu(Wa1^T @ t^T + ba1 (in C))
    f32x4 ba1v[4];
#pragma unroll
    for (int tm = 0; tm < 4; ++tm)
        ba1v[tm] = *(const f32x4*)(ba1 + tm * 16 + q4 * 4);
    f32x4 acc[4][2];
#pragma unroll
    for (int tm = 0; tm < 4; ++tm)
#pragma unroll
        for (int tn = 0; tn < 2; ++tn) acc[tm][tn] = ba1v[tm];
#pragma unroll
    for (int ks = 0; ks < 2; ++ks) {
        short8 aw[4];
#pragma unroll
        for (int tm = 0; tm < 4; ++tm)
            aw[tm] = ldfrag(lds, O_WA1, tm * 16 + lid, ks * 64 + kb, 7, 7);
#pragma unroll
        for (int tn = 0; tn < 2; ++tn) {
            int j = (jt0 + tn) * 16 + lid;
            short8 bf = ldfrag(lds, O_TH, j, ks * 64 + kb, 7, 7);
#pragma unroll
            for (int tm = 0; tm < 4; ++tm)
                acc[tm][tn] = __builtin_amdgcn_mfma_f32_16x16x32_bf16(aw[tm], bf, acc[tm][tn], 0, 0, 0);
        }
    }

    // ---- hoist v loads (consumed in softmax, hidden under GEMM3-epi + GEMM4)
    f32x4 v4h[4][2];
#pragma unroll
    for (int tm = 0; tm < 4; ++tm) {
        int ch0 = tm * 16 + q4 * 4;
#pragma unroll
        for (int tn = 0; tn < 2; ++tn) {
            int j = (jt0 + tn) * 16 + lid;
            v4h[tm][tn] = *(const f32x4*)(kvb + (size_t)j * 192 + 128 + ch0);
        }
    }

#pragma unroll
    for (int tm = 0; tm < 4; ++tm)
#pragma unroll
        for (int tn = 0; tn < 2; ++tn) {
            int j = (jt0 + tn) * 16 + lid;
            uint2 w;
            w.x = cvtpk(fmaxf(acc[tm][tn][0], 0.f), fmaxf(acc[tm][tn][1], 0.f));
            w.y = cvtpk(fmaxf(acc[tm][tn][2], 0.f), fmaxf(acc[tm][tn][3], 0.f));
            *(uint2*)(lds + O_TH + swb(j, tm * 32 + q4 * 8, 7, 7)) = w;
        }

    // ---- GEMM4: sim = Wa2^T @ h2^T (ba2 cancels in softmax)
#pragma unroll
    for (int tm = 0; tm < 4; ++tm)
#pragma unroll
        for (int tn = 0; tn < 2; ++tn) acc[tm][tn] = z4;
#pragma unroll
    for (int ks = 0; ks < 2; ++ks) {
        short8 aw[4];
#pragma unroll
        for (int tm = 0; tm < 4; ++tm)
            aw[tm] = ldfrag(lds, O_WA2, tm * 16 + lid, ks * 64 + kb, 7, 7);
#pragma unroll
        for (int tn = 0; tn < 2; ++tn) {
            int j = (jt0 + tn) * 16 + lid;
            short8 bf = ldfrag(lds, O_TH, j, ks * 64 + kb, 7, 7);
#pragma unroll
            for (int tm = 0; tm < 4; ++tm)
                acc[tm][tn] = __builtin_amdgcn_mfma_f32_16x16x32_bf16(aw[tm], bf, acc[tm][tn], 0, 0, 0);
        }
    }

    // ---- softmax over j + weighted (v + rel) sum
#pragma unroll
    for (int tm = 0; tm < 4; ++tm) {
        f32x4 num = z4, den = z4;
#pragma unroll
        for (int tn = 0; tn < 2; ++tn) {
#pragma unroll
            for (int g = 0; g < 4; ++g) {
                float ev = __expf(acc[tm][tn][g]);
                den[g] += ev;
                num[g] = fmaf(ev, v4h[tm][tn][g] + rel[tm][tn][g], num[g]);
            }
        }
#pragma unroll
        for (int ofs = 1; ofs < 16; ofs <<= 1) {
#pragma unroll
            for (int g = 0; g < 4; ++g) {
                num[g] += __shfl_xor(num[g], ofs);
                den[g] += __shfl_xor(den[g], ofs);
            }
        }
        if (lid == 0) {
            int base = O_RED + ((wv * 4 + tm) * 4 + q4) * 32;
            *(f32x4*)(lds + base) = num;
            *(f32x4*)(lds + base + 16) = den;
        }
    }
    __syncthreads();

    if (tid < 64) {
        int tm = tid >> 4, qq = (tid >> 2) & 3, g = tid & 3;
        float nn = 0.f, dd = 0.f;
#pragma unroll
        for (int w = 0; w < 8; ++w) {
            int base = O_RED + ((w * 4 + tm) * 4 + qq) * 32 + g * 4;
            nn += *(const float*)(lds + base);
            dd += *(const float*)(lds + base + 16);
        }
        agg[(size_t)n * 64 + tid] = nn / dd;
    }
}

// ---------------- Kernel C: out = relu(BN(agg@W2+b2) + skip) ----------------
__global__ __launch_bounds__(256) void fc2_kernel(
    const float* __restrict__ agg, const float* __restrict__ W2, const float* __restrict__ b2,
    const float* __restrict__ g2, const float* __restrict__ bb2,
    const float* __restrict__ m2, const float* __restrict__ v2,
    const float* __restrict__ skip, float* __restrict__ out)
{
    const int ROWS = 8;
    __shared__ float ar[ROWS][INNER];
    const int n0 = blockIdx.x * ROWS;
    const int t = threadIdx.x;

    for (int idx = t; idx < ROWS * INNER; idx += 256)
        ((float*)ar)[idx] = agg[(size_t)n0 * INNER + idx];
    __syncthreads();

    const float s2 = g2[t] * rsqrtf(v2[t] + EPSV);
    const float base = b2[t] - m2[t];
    const float bet = bb2[t];

    float accv[ROWS];
#pragma unroll
    for (int rr = 0; rr < ROWS; ++rr) accv[rr] = 0.f;
    for (int k = 0; k < INNER; ++k) {
        float wv = W2[(size_t)k * CC + t];
#pragma unroll
        for (int rr = 0; rr < ROWS; ++rr) accv[rr] = fmaf(ar[rr][k], wv, accv[rr]);
    }
#pragma unroll
    for (int rr = 0; rr < ROWS; ++rr) {
        float y = (accv[rr] + base) * s2 + bet;
        out[(size_t)(n0 + rr) * CC + t] =
            fmaxf(y + skip[(size_t)(n0 + rr) * CC + t], 0.f);
    }
}

extern "C" void kernel_launch(void* const* d_in, const int* in_sizes, int n_in,
                              void* d_out, int out_size, void* d_ws, size_t ws_size,
                              hipStream_t stream)
{
    const float* x   = (const float*)d_in[0];
    const float* r   = (const float*)d_in[1];
    const float* W1  = (const float*)d_in[2];
    const float* b1  = (const float*)d_in[3];
    const float* g1  = (const float*)d_in[4];
    const float* bb1 = (const float*)d_in[5];
    const float* m1  = (const float*)d_in[6];
    const float* v1  = (const float*)d_in[7];
    const float* Wqkv= (const float*)d_in[8];
    const float* Wt1 = (const float*)d_in[9];
    const float* bt1 = (const float*)d_in[10];
    const float* gt  = (const float*)d_in[11];
    const float* bbt = (const float*)d_in[12];
    const float* mt  = (const float*)d_in[13];
    const float* vt  = (const float*)d_in[14];
    const float* Wt2 = (const float*)d_in[15];
    const float* bt2 = (const float*)d_in[16];
    const float* Wa1 = (const float*)d_in[17];
    const float* ba1 = (const float*)d_in[18];
    const float* Wa2 = (const float*)d_in[19];
    const float* W2  = (const float*)d_in[21];
    const float* b2  = (const float*)d_in[22];
    const float* g2  = (const float*)d_in[23];
    const float* bb2 = (const float*)d_in[24];
    const float* m2  = (const float*)d_in[25];
    const float* v2  = (const float*)d_in[26];
    float* out = (float*)d_out;

    const int N = BB * TT;                 // 4096 rows
    float* skip = (float*)d_ws;            // N*256 floats
    float* qkv  = skip + (size_t)N * CC;   // N*192 floats
    float* agg  = qkv  + (size_t)N * 192;  // N*64  floats
    char*  img  = (char*)(agg + (size_t)N * 64);  // 22.7KB weight image

    prep_kernel<<<dim3(4), dim3(256), 0, stream>>>(
        Wt1, bt1, gt, bbt, mt, vt, Wt2, Wa1, Wa2, img);
    fc1_qkv_kernel<<<dim3(N / 8), dim3(256), 0, stream>>>(
        x, W1, b1, g1, bb1, m1, v1, Wqkv, skip, qkv);
    attn_mfma_kernel<<<dim3(N), dim3(512), 0, stream>>>(
        r, qkv, bt2, ba1, img, agg);
    fc2_kernel<<<dim3(N / 8), dim3(256), 0, stream>>>(
        agg, W2, b2, g2, bb2, m2, v2, skip, out);
}